// Round 7
// baseline (370.590 us; speedup 1.0000x reference)
//
#include <hip/hip_runtime.h>
#include <hip/hip_bf16.h>
#include <math.h>

// Problem constants (B=2, H=12, S=2048, D=64, hash_code_len=8)
#define NB 2
#define NH 12
#define NS 2048
#define ND 64
#define NBH (NB * NH)
#define TILE_USHORT 4096        // one 64x64 bf16 tile image = 8 KB
#define QK_BLOCKS 6144          // prep: 2*NBH*NS rows / 16 rows per block
#define V_BLOCKS (NBH * 32)     // 768

typedef __attribute__((ext_vector_type(8))) short short8;   // MFMA A/B frag
typedef __attribute__((ext_vector_type(4))) float floatx4;  // MFMA C/D frag
typedef __attribute__((ext_vector_type(2))) float float2v;  // packed f32 pair

__device__ __forceinline__ unsigned short f32_to_bf16_rne(float f) {
  unsigned int u = __float_as_uint(f);
  u += 0x7fffu + ((u >> 16) & 1u);
  return (unsigned short)(u >> 16);
}

// pack two f32 -> two bf16 (truncate) in ONE v_perm_b32 (lo -> low half).
__device__ __forceinline__ unsigned int pack_bf16_trunc(float lo, float hi) {
  return __builtin_amdgcn_perm(__float_as_uint(hi), __float_as_uint(lo), 0x07060302);
}

__device__ __forceinline__ float2v mk2(float x) { return (float2v){x, x}; }
__device__ __forceinline__ float2v max2(float2v a, float2v b) {
  return (float2v){fmaxf(a[0], b[0]), fmaxf(a[1], b[1])};
}
__device__ __forceinline__ float2v abs2(float2v a) {
  return (float2v){fabsf(a[0]), fabsf(a[1])};
}

// exact-ish fallback: 1 - acos(d)/pi via A&S 4.4.45 (valid on full [-1,1])
__device__ __forceinline__ float yoso_f_exact(float d) {
  const float c0 = 0.49996030f;
  const float c1 = -0.06751822f;
  const float c2 = 0.02363774f;
  const float c3 = -0.00596174f;
  float a = fminf(fabsf(d), 1.0f);
  float p = fmaf(fmaf(fmaf(c3, a, c2), a, c1), a, c0);
  float u = sqrtf(1.0f - a) * p;
  return (d >= 0.0f) ? (1.0f - u) : u;
}

// ---------------------------------------------------------------------------
// Fragment-order tile images (per 64x64 bf16 tile, 8 KB):
//   frag_id in [0,8): 1 KB each; within a frag: lane*16B + j*2B.
// Q/K (rows n = q|t, cols k = d):
//   frag_id = (d>>5)*4 + (n>>4); lane = ((d>>3)&3)*16 + (n&15); j = d&7.
// V (MFMA#2 A-operand, k-positions permuted to match register-resident W^T):
//   frag_id = (t>>5)*4 + (d>>4); lane = ((t>>2)&3)*16 + (d&15);
//   j = ((t>>4)&1)*4 + (t&3).  Key mask folded in: stores m_t * V[t][d].
// ---------------------------------------------------------------------------
__global__ __launch_bounds__(256) void prep_all(
    const float* __restrict__ Q, const float* __restrict__ K,
    const float* __restrict__ V, const float* __restrict__ mask,
    unsigned short* __restrict__ qimg, unsigned short* __restrict__ kimg,
    unsigned short* __restrict__ vimg) {
  int blk = blockIdx.x;
  if (blk < QK_BLOCKS) {
    int row = blk * 16 + (threadIdx.x >> 4);
    int li  = threadIdx.x & 15;
    const float* src = Q;
    unsigned short* dst = qimg;
    if (row >= NBH * NS) { src = K; dst = kimg; row -= NBH * NS; }
    float4 v = *(const float4*)(src + (size_t)row * ND + li * 4);
    float ss = v.x * v.x + v.y * v.y + v.z * v.z + v.w * v.w;
    ss += __shfl_xor(ss, 1, 64);
    ss += __shfl_xor(ss, 2, 64);
    ss += __shfl_xor(ss, 4, 64);
    ss += __shfl_xor(ss, 8, 64);
    float rn = 1.0f / fmaxf(sqrtf(ss), 1e-12f);
    ushort4 o;
    o.x = f32_to_bf16_rne(v.x * rn);
    o.y = f32_to_bf16_rne(v.y * rn);
    o.z = f32_to_bf16_rne(v.z * rn);
    o.w = f32_to_bf16_rne(v.w * rn);
    int bh = row >> 11;            // / NS
    int s  = row & (NS - 1);
    int kt = s >> 6, r = s & 63;
    // d = li*4 .. li*4+3
    int frag = (li >> 3) * 4 + (r >> 4);
    int ln   = ((li >> 1) & 3) * 16 + (r & 15);
    size_t off = (size_t)(bh * 32 + kt) * TILE_USHORT + frag * 512 + ln * 8 + (li & 1) * 4;
    *(ushort4*)(dst + off) = o;
  } else {
    int vb = blk - QK_BLOCKS;
    int bh = vb >> 5, kt = vb & 31, t0 = kt * 64;
    int b  = bh / NH;
    __shared__ float sT[64][65];   // [d][t], mask folded in
    int tid = threadIdx.x;
    int tr = tid >> 2;             // t within tile
    int dc = (tid & 3) * 16;       // d start
    float m = mask[b * NS + t0 + tr];
    const float* vp = V + ((size_t)bh * NS + t0 + tr) * ND + dc;
    #pragma unroll
    for (int jj = 0; jj < 16; jj += 4) {
      float4 v = *(const float4*)(vp + jj);
      sT[dc + jj + 0][tr] = v.x * m;
      sT[dc + jj + 1][tr] = v.y * m;
      sT[dc + jj + 2][tr] = v.z * m;
      sT[dc + jj + 3][tr] = v.w * m;
    }
    __syncthreads();
    int dr = tid >> 2;             // d row, 0..63
    unsigned short* op = vimg + (size_t)(bh * 32 + kt) * TILE_USHORT;
    #pragma unroll
    for (int g = 0; g < 2; ++g) {
      int combo = (tid & 3) * 2 + g;   // 0..7
      int kk2 = combo >> 2;            // t>>5
      int qd  = combo & 3;             // (t>>2)&3
      // j = w*4 + i  <->  t = kk2*32 + w*16 + qd*4 + i
      uint4 u;
      int tb = kk2 * 32 + qd * 4;
      u.x = (unsigned int)f32_to_bf16_rne(sT[dr][tb + 0]) |
            ((unsigned int)f32_to_bf16_rne(sT[dr][tb + 1]) << 16);
      u.y = (unsigned int)f32_to_bf16_rne(sT[dr][tb + 2]) |
            ((unsigned int)f32_to_bf16_rne(sT[dr][tb + 3]) << 16);
      u.z = (unsigned int)f32_to_bf16_rne(sT[dr][tb + 16]) |
            ((unsigned int)f32_to_bf16_rne(sT[dr][tb + 17]) << 16);
      u.w = (unsigned int)f32_to_bf16_rne(sT[dr][tb + 18]) |
            ((unsigned int)f32_to_bf16_rne(sT[dr][tb + 19]) << 16);
      int frag = kk2 * 4 + (dr >> 4);
      int ln   = qd * 16 + (dr & 15);
      *(uint4*)(op + frag * 512 + ln * 8) = u;
    }
  }
}

// ---------------------------------------------------------------------------
// Main. Block = (bh, 64-q tile), 512 threads = 8 waves: qh = wv&1 (32 q rows),
// kp = wv>>1 in [0,4) (key tiles kt = 4*ss+kp, 8 iters). Per-wave body is the
// R5 structure (no reg prefetch — that spills; no LDS staging — no barriers in
// the k-loop). 6 waves/SIMD (vs 3) hide K-load latency + transform fma chains.
// Epilogue: 2-round LDS butterfly over kp, l2norm, + conv3, store.
// ---------------------------------------------------------------------------
__global__ __launch_bounds__(512, 6) void yoso_main(
    const unsigned short* __restrict__ qimg, const unsigned short* __restrict__ kimg,
    const unsigned short* __restrict__ vimg, const float* __restrict__ V,
    const float* __restrict__ mask, const float* __restrict__ conv_w,
    float* __restrict__ out) {
  int bh = blockIdx.x >> 5;
  int b  = bh / NH;
  int h  = bh % NH;
  int qt = blockIdx.x & 31;
  int s0 = qt * 64;

  __shared__ float xch[4 * 2176];   // exchange, stride-68 padded (34.8 KB)

  int tid  = threadIdx.x;
  int wv   = tid >> 6;       // 0..7
  int lane = tid & 63;
  int lq   = lane & 15;
  int quad = lane >> 4;
  int qh   = wv & 1;
  int kp   = wv >> 1;        // 0..3

  // Loop-invariant Q fragments (B-operand: n=q rows qh*32+su*16+lq).
  uint4 qfrag[2][2];   // [su][kk]
  {
    const unsigned short* qtile = qimg + (size_t)(bh * 32 + qt) * TILE_USHORT;
    #pragma unroll
    for (int su = 0; su < 2; ++su)
      #pragma unroll
      for (int kk = 0; kk < 2; ++kk)
        qfrag[su][kk] = *(const uint4*)(qtile + (kk * 4 + qh * 2 + su) * 512 + lane * 8);
  }

  float w0 = conv_w[h * 3 + 0], w1 = conv_w[h * 3 + 1], w2 = conv_w[h * 3 + 2];

  floatx4 acc[2][4];   // [su][fd]: X^T, d = fd*16 + quad*4 + r, q = su*16+lq
  #pragma unroll
  for (int su = 0; su < 2; ++su)
    #pragma unroll
    for (int fd = 0; fd < 4; ++fd) acc[su][fd] = (floatx4){0.f, 0.f, 0.f, 0.f};

  const unsigned short* kb  = kimg + (size_t)bh * 32 * TILE_USHORT;
  const unsigned short* vbI = vimg + (size_t)bh * 32 * TILE_USHORT;

  // asin(x)/pi odd-Taylor coefficients (to x^11), on y = x^2
  const float P0 = 0.3183098862f;
  const float P1 = 0.0530516477f;
  const float P2 = 0.0238732415f;
  const float P3 = 0.0142098402f;
  const float P4 = 0.0096701727f;
  const float P5 = 0.0071212906f;

  #pragma unroll 1
  for (int ss = 0; ss < 8; ++ss) {
    int kt = ss * 4 + kp;
    const unsigned short* ktile = kb  + (size_t)kt * TILE_USHORT;
    const unsigned short* vtile = vbI + (size_t)kt * TILE_USHORT;

    // --- K fragments (8 x contiguous 1 KB) + MFMA#1: S^T = K·Q^T ---
    uint4 kf[2][4];
    #pragma unroll
    for (int kk = 0; kk < 2; ++kk)
      #pragma unroll
      for (int ft = 0; ft < 4; ++ft)
        kf[kk][ft] = *(const uint4*)(ktile + (kk * 4 + ft) * 512 + lane * 8);

    floatx4 sc[2][4];   // [su][ft]: t = ft*16 + quad*4 + r, q = su*16+lq
    #pragma unroll
    for (int su = 0; su < 2; ++su)
      #pragma unroll
      for (int ft = 0; ft < 4; ++ft) sc[su][ft] = (floatx4){0.f, 0.f, 0.f, 0.f};
    #pragma unroll
    for (int kk = 0; kk < 2; ++kk)
      #pragma unroll
      for (int su = 0; su < 2; ++su) {
        short8 bq = *(const short8*)&qfrag[su][kk];
        #pragma unroll
        for (int ft = 0; ft < 4; ++ft)
          sc[su][ft] = __builtin_amdgcn_mfma_f32_16x16x32_bf16(
              *(const short8*)&kf[kk][ft], bq, sc[su][ft], 0, 0, 0);
      }

    // --- V fragments: issue now; latency hides under the transform ---
    uint4 vf[2][4];
    #pragma unroll
    for (int kk2 = 0; kk2 < 2; ++kk2)
      #pragma unroll
      for (int fd = 0; fd < 4; ++fd)
        vf[kk2][fd] = *(const uint4*)(vtile + (kk2 * 4 + fd) * 512 + lane * 8);

    // --- transform in place: sc := W = (1/2 + asin(d)/pi)^8 (packed f32) ---
    {
      float2v mxy = mk2(0.f);
      #pragma unroll
      for (int su = 0; su < 2; ++su)
        #pragma unroll
        for (int ft = 0; ft < 4; ++ft) {
          float2v* p = (float2v*)&sc[su][ft];
          mxy = max2(mxy, max2(abs2(p[0]), abs2(p[1])));
        }
      float mx = fmaxf(mxy[0], mxy[1]);
      if (__builtin_expect(__any(mx > 0.82f), 0)) {
        #pragma unroll
        for (int su = 0; su < 2; ++su)
          #pragma unroll
          for (int ft = 0; ft < 4; ++ft)
            #pragma unroll
            for (int r = 0; r < 4; ++r) {
              float f = yoso_f_exact(sc[su][ft][r]);
              float f2 = f * f;
              float f4 = f2 * f2;
              sc[su][ft][r] = f4 * f4;
            }
      } else {
        float2v c5 = mk2(P5), c4 = mk2(P4), c3 = mk2(P3), c2 = mk2(P2),
                c1 = mk2(P1), c0 = mk2(P0), hf = mk2(0.5f);
        #pragma unroll
        for (int su = 0; su < 2; ++su)
          #pragma unroll
          for (int ft = 0; ft < 4; ++ft) {
            float2v* p = (float2v*)&sc[su][ft];
            #pragma unroll
            for (int hh = 0; hh < 2; ++hh) {
              float2v d = p[hh];
              float2v y = d * d;
              float2v pp = ((((c5 * y + c4) * y + c3) * y + c2) * y + c1) * y + c0;
              float2v f = pp * d + hf;
              float2v f2 = f * f;
              float2v f4 = f2 * f2;
              p[hh] = f4 * f4;
            }
          }
      }
    }

    // --- MFMA#2: X^T += Vm^T · W^T (consumes vf) ---
    #pragma unroll
    for (int kk2 = 0; kk2 < 2; ++kk2)
      #pragma unroll
      for (int su = 0; su < 2; ++su) {
        uint4 u;
        u.x = pack_bf16_trunc(sc[su][2 * kk2][0], sc[su][2 * kk2][1]);
        u.y = pack_bf16_trunc(sc[su][2 * kk2][2], sc[su][2 * kk2][3]);
        u.z = pack_bf16_trunc(sc[su][2 * kk2 + 1][0], sc[su][2 * kk2 + 1][1]);
        u.w = pack_bf16_trunc(sc[su][2 * kk2 + 1][2], sc[su][2 * kk2 + 1][3]);
        short8 bw = *(short8*)&u;
        #pragma unroll
        for (int fd = 0; fd < 4; ++fd)
          acc[su][fd] = __builtin_amdgcn_mfma_f32_16x16x32_bf16(
              *(const short8*)&vf[kk2][fd], bw, acc[su][fd], 0, 0, 0);
      }
  }

  // --- Round 1: kp>=2 export full acc; kp<2 add (partner wv+4) ---
  __syncthreads();
  if (kp >= 2) {
    float* wr = xch + (wv - 4) * 2176;
    #pragma unroll
    for (int su = 0; su < 2; ++su)
      #pragma unroll
      for (int fd = 0; fd < 4; ++fd)
        #pragma unroll
        for (int r = 0; r < 4; ++r)
          wr[su * 1088 + lq * 68 + fd * 16 + quad * 4 + r] = acc[su][fd][r];
  }
  __syncthreads();
  if (kp < 2) {
    const float* rd = xch + wv * 2176;
    #pragma unroll
    for (int su = 0; su < 2; ++su)
      #pragma unroll
      for (int fd = 0; fd < 4; ++fd)
        #pragma unroll
        for (int r = 0; r < 4; ++r)
          acc[su][fd][r] += rd[su * 1088 + lq * 68 + fd * 16 + quad * 4 + r];
  }
  __syncthreads();
  // --- Round 2: among kp<2: export su=1-kp, keep su=kp (partner wv^2) ---
  if (kp < 2) {
    float* wr = xch + wv * 1088;
    #pragma unroll
    for (int fd = 0; fd < 4; ++fd)
      #pragma unroll
      for (int r = 0; r < 4; ++r)
        wr[lq * 68 + fd * 16 + quad * 4 + r] = acc[1 - kp][fd][r];
  }
  __syncthreads();
  if (kp < 2) {
    const float* rd = xch + (wv ^ 2) * 1088;
    #pragma unroll
    for (int fd = 0; fd < 4; ++fd)
      #pragma unroll
      for (int r = 0; r < 4; ++r)
        acc[kp][fd][r] += rd[lq * 68 + fd * 16 + quad * 4 + r];

    // --- epilogue: this wave finishes q = s0 + qh*32 + kp*16 + lq ---
    int s = s0 + qh * 32 + kp * 16 + lq;
    float qm  = mask[b * NS + s];
    float qm0 = (s > 0) ? mask[b * NS + s - 1] : 0.f;
    float qm2 = (s < NS - 1) ? mask[b * NS + s + 1] : 0.f;
    float ssum = 0.f;
    #pragma unroll
    for (int fd = 0; fd < 4; ++fd)
      #pragma unroll
      for (int r = 0; r < 4; ++r) {
        float x = acc[kp][fd][r] * qm;
        acc[kp][fd][r] = x;
        ssum += x * x;
      }
    ssum += __shfl_xor(ssum, 16, 64);
    ssum += __shfl_xor(ssum, 32, 64);
    float rn = 1.0f / fmaxf(sqrtf(ssum), 1e-12f);

    const float* vfull = V + ((size_t)bh * NS + s) * ND;
    #pragma unroll
    for (int fd = 0; fd < 4; ++fd) {
      int d = fd * 16 + quad * 4;
      float4 vc1 = *(const float4*)(vfull + d);
      float4 cv;
      cv.x = w1 * vc1.x * qm; cv.y = w1 * vc1.y * qm;
      cv.z = w1 * vc1.z * qm; cv.w = w1 * vc1.w * qm;
      if (s > 0) {
        float4 vc0 = *(const float4*)(vfull - ND + d);
        cv.x += w0 * vc0.x * qm0; cv.y += w0 * vc0.y * qm0;
        cv.z += w0 * vc0.z * qm0; cv.w += w0 * vc0.w * qm0;
      }
      if (s < NS - 1) {
        float4 vc2 = *(const float4*)(vfull + ND + d);
        cv.x += w2 * vc2.x * qm2; cv.y += w2 * vc2.y * qm2;
        cv.z += w2 * vc2.z * qm2; cv.w += w2 * vc2.w * qm2;
      }
      float4 o;
      o.x = acc[kp][fd][0] * rn + cv.x;
      o.y = acc[kp][fd][1] * rn + cv.y;
      o.z = acc[kp][fd][2] * rn + cv.z;
      o.w = acc[kp][fd][3] * rn + cv.w;
      *(float4*)(out + ((size_t)bh * NS + s) * ND + d) = o;
    }
  }
}

// ---------------------------------------------------------------------------
extern "C" void kernel_launch(void* const* d_in, const int* in_sizes, int n_in,
                              void* d_out, int out_size, void* d_ws, size_t ws_size,
                              hipStream_t stream) {
  const float* Q      = (const float*)d_in[0];
  const float* K      = (const float*)d_in[1];
  const float* V      = (const float*)d_in[2];
  const float* mask   = (const float*)d_in[3];
  const float* conv_w = (const float*)d_in[4];
  float* out = (float*)d_out;

  const size_t seg = (size_t)NBH * NS * ND * sizeof(unsigned short);  // 6.29 MB
  unsigned short* qimg = (unsigned short*)d_ws;
  unsigned short* kimg = (unsigned short*)((char*)d_ws + seg);
  unsigned short* vimg = (unsigned short*)((char*)d_ws + 2 * seg);

  prep_all<<<QK_BLOCKS + V_BLOCKS, 256, 0, stream>>>(Q, K, V, mask, qimg, kimg, vimg);
  yoso_main<<<NBH * 32, 512, 0, stream>>>(qimg, kimg, vimg, V, mask, conv_w, out);
}

// Round 8
// 146.444 us; speedup vs baseline: 2.5306x; 2.5306x over previous
//
#include <hip/hip_runtime.h>
#include <hip/hip_bf16.h>
#include <math.h>

// Problem constants (B=2, H=12, S=2048, D=64, hash_code_len=8)
#define NB 2
#define NH 12
#define NS 2048
#define ND 64
#define NBH (NB * NH)
#define TILE_USHORT 4096        // one 64x64 bf16 tile image = 8 KB
#define QK_BLOCKS 6144          // prep: 2*NBH*NS rows / 16 rows per block
#define V_BLOCKS (NBH * 32)     // 768

typedef __attribute__((ext_vector_type(8))) short short8;   // MFMA A/B frag
typedef __attribute__((ext_vector_type(4))) float floatx4;  // MFMA C/D frag
typedef __attribute__((ext_vector_type(2))) float float2v;  // packed f32 pair

__device__ __forceinline__ unsigned short f32_to_bf16_rne(float f) {
  unsigned int u = __float_as_uint(f);
  u += 0x7fffu + ((u >> 16) & 1u);
  return (unsigned short)(u >> 16);
}

// pack two f32 -> two bf16 (truncate) in ONE v_perm_b32 (lo -> low half).
__device__ __forceinline__ unsigned int pack_bf16_trunc(float lo, float hi) {
  return __builtin_amdgcn_perm(__float_as_uint(hi), __float_as_uint(lo), 0x07060302);
}

__device__ __forceinline__ float2v mk2(float x) { return (float2v){x, x}; }
__device__ __forceinline__ float2v max2(float2v a, float2v b) {
  return (float2v){fmaxf(a[0], b[0]), fmaxf(a[1], b[1])};
}
__device__ __forceinline__ float2v abs2(float2v a) {
  return (float2v){fabsf(a[0]), fabsf(a[1])};
}

// exact-ish fallback: 1 - acos(d)/pi via A&S 4.4.45 (valid on full [-1,1])
__device__ __forceinline__ float yoso_f_exact(float d) {
  const float c0 = 0.49996030f;
  const float c1 = -0.06751822f;
  const float c2 = 0.02363774f;
  const float c3 = -0.00596174f;
  float a = fminf(fabsf(d), 1.0f);
  float p = fmaf(fmaf(fmaf(c3, a, c2), a, c1), a, c0);
  float u = sqrtf(1.0f - a) * p;
  return (d >= 0.0f) ? (1.0f - u) : u;
}

// ---------------------------------------------------------------------------
// Fragment-order tile images (per 64x64 bf16 tile, 8 KB):
//   frag_id in [0,8): 1 KB each; within a frag: lane*16B + j*2B.
// Q/K (rows n = q|t, cols k = d):
//   frag_id = (d>>5)*4 + (n>>4); lane = ((d>>3)&3)*16 + (n&15); j = d&7.
// V (MFMA#2 A-operand, k-positions permuted to match register-resident W^T):
//   frag_id = (t>>5)*4 + (d>>4); lane = ((t>>2)&3)*16 + (d&15);
//   j = ((t>>4)&1)*4 + (t&3).  Key mask folded in: stores m_t * V[t][d].
// ---------------------------------------------------------------------------
__global__ __launch_bounds__(256) void prep_all(
    const float* __restrict__ Q, const float* __restrict__ K,
    const float* __restrict__ V, const float* __restrict__ mask,
    unsigned short* __restrict__ qimg, unsigned short* __restrict__ kimg,
    unsigned short* __restrict__ vimg) {
  int blk = blockIdx.x;
  if (blk < QK_BLOCKS) {
    int row = blk * 16 + (threadIdx.x >> 4);
    int li  = threadIdx.x & 15;
    const float* src = Q;
    unsigned short* dst = qimg;
    if (row >= NBH * NS) { src = K; dst = kimg; row -= NBH * NS; }
    float4 v = *(const float4*)(src + (size_t)row * ND + li * 4);
    float ss = v.x * v.x + v.y * v.y + v.z * v.z + v.w * v.w;
    ss += __shfl_xor(ss, 1, 64);
    ss += __shfl_xor(ss, 2, 64);
    ss += __shfl_xor(ss, 4, 64);
    ss += __shfl_xor(ss, 8, 64);
    float rn = 1.0f / fmaxf(sqrtf(ss), 1e-12f);
    ushort4 o;
    o.x = f32_to_bf16_rne(v.x * rn);
    o.y = f32_to_bf16_rne(v.y * rn);
    o.z = f32_to_bf16_rne(v.z * rn);
    o.w = f32_to_bf16_rne(v.w * rn);
    int bh = row >> 11;            // / NS
    int s  = row & (NS - 1);
    int kt = s >> 6, r = s & 63;
    // d = li*4 .. li*4+3
    int frag = (li >> 3) * 4 + (r >> 4);
    int ln   = ((li >> 1) & 3) * 16 + (r & 15);
    size_t off = (size_t)(bh * 32 + kt) * TILE_USHORT + frag * 512 + ln * 8 + (li & 1) * 4;
    *(ushort4*)(dst + off) = o;
  } else {
    int vb = blk - QK_BLOCKS;
    int bh = vb >> 5, kt = vb & 31, t0 = kt * 64;
    int b  = bh / NH;
    __shared__ float sT[64][65];   // [d][t], mask folded in
    int tid = threadIdx.x;
    int tr = tid >> 2;             // t within tile
    int dc = (tid & 3) * 16;       // d start
    float m = mask[b * NS + t0 + tr];
    const float* vp = V + ((size_t)bh * NS + t0 + tr) * ND + dc;
    #pragma unroll
    for (int jj = 0; jj < 16; jj += 4) {
      float4 v = *(const float4*)(vp + jj);
      sT[dc + jj + 0][tr] = v.x * m;
      sT[dc + jj + 1][tr] = v.y * m;
      sT[dc + jj + 2][tr] = v.z * m;
      sT[dc + jj + 3][tr] = v.w * m;
    }
    __syncthreads();
    int dr = tid >> 2;             // d row, 0..63
    unsigned short* op = vimg + (size_t)(bh * 32 + kt) * TILE_USHORT;
    #pragma unroll
    for (int g = 0; g < 2; ++g) {
      int combo = (tid & 3) * 2 + g;   // 0..7
      int kk2 = combo >> 2;            // t>>5
      int qd  = combo & 3;             // (t>>2)&3
      // j = w*4 + i  <->  t = kk2*32 + w*16 + qd*4 + i
      uint4 u;
      int tb = kk2 * 32 + qd * 4;
      u.x = (unsigned int)f32_to_bf16_rne(sT[dr][tb + 0]) |
            ((unsigned int)f32_to_bf16_rne(sT[dr][tb + 1]) << 16);
      u.y = (unsigned int)f32_to_bf16_rne(sT[dr][tb + 2]) |
            ((unsigned int)f32_to_bf16_rne(sT[dr][tb + 3]) << 16);
      u.z = (unsigned int)f32_to_bf16_rne(sT[dr][tb + 16]) |
            ((unsigned int)f32_to_bf16_rne(sT[dr][tb + 17]) << 16);
      u.w = (unsigned int)f32_to_bf16_rne(sT[dr][tb + 18]) |
            ((unsigned int)f32_to_bf16_rne(sT[dr][tb + 19]) << 16);
      int frag = kk2 * 4 + (dr >> 4);
      int ln   = qd * 16 + (dr & 15);
      *(uint4*)(op + frag * 512 + ln * 8) = u;
    }
  }
}

// ---------------------------------------------------------------------------
// Main. Block = (bh, 32-q tile) -> grid 1536 (6 blocks/CU, 24 waves/CU).
// 4 waves: qs = wv&1 (q rows qs*16..+15), kp = wv>>1 (key tiles kt=2*ss+kp).
// Per-wave body = R5 structure at half size (~60 VGPRs, no forced cap):
//   MFMA#1: S^T = K·Q^T -> V-frag loads issued (hide under transform) ->
//   packed-f32 transform in regs -> MFMA#2: X^T += Vm^T·W^T.
// Epilogue: one LDS round over kp, l2norm, + conv3, store.
// ---------------------------------------------------------------------------
__global__ __launch_bounds__(256, 4) void yoso_main(
    const unsigned short* __restrict__ qimg, const unsigned short* __restrict__ kimg,
    const unsigned short* __restrict__ vimg, const float* __restrict__ V,
    const float* __restrict__ mask, const float* __restrict__ conv_w,
    float* __restrict__ out) {
  int bh = blockIdx.x >> 6;          // 64 q-tiles of 32 rows per bh
  int b  = bh / NH;
  int h  = bh % NH;
  int qt = blockIdx.x & 63;
  int s0 = qt * 32;

  __shared__ float xch[2 * 1088];    // exchange, stride-68 padded (8.7 KB)

  int tid  = threadIdx.x;
  int wv   = tid >> 6;       // 0..3
  int lane = tid & 63;
  int lq   = lane & 15;
  int quad = lane >> 4;
  int qs   = wv & 1;         // q half (16 rows)
  int kp   = wv >> 1;        // key parity

  // Loop-invariant Q fragment (B-operand: n = q rows qt*32 + qs*16 + lq).
  uint4 qfrag[2];   // [kk]
  {
    const unsigned short* qtile = qimg + (size_t)(bh * 32 + (qt >> 1)) * TILE_USHORT;
    int nb = (qt & 1) * 2 + qs;      // (row within 64-row image tile) >> 4
    #pragma unroll
    for (int kk = 0; kk < 2; ++kk)
      qfrag[kk] = *(const uint4*)(qtile + (kk * 4 + nb) * 512 + lane * 8);
  }

  float w0 = conv_w[h * 3 + 0], w1 = conv_w[h * 3 + 1], w2 = conv_w[h * 3 + 2];

  floatx4 acc[4];   // [fd]: X^T, d = fd*16 + quad*4 + r, q = lq
  #pragma unroll
  for (int fd = 0; fd < 4; ++fd) acc[fd] = (floatx4){0.f, 0.f, 0.f, 0.f};

  const unsigned short* kb  = kimg + (size_t)bh * 32 * TILE_USHORT;
  const unsigned short* vbI = vimg + (size_t)bh * 32 * TILE_USHORT;

  // asin(x)/pi odd-Taylor coefficients (to x^11), on y = x^2
  const float P0 = 0.3183098862f;
  const float P1 = 0.0530516477f;
  const float P2 = 0.0238732415f;
  const float P3 = 0.0142098402f;
  const float P4 = 0.0096701727f;
  const float P5 = 0.0071212906f;

  #pragma unroll 1
  for (int ss = 0; ss < 16; ++ss) {
    int kt = ss * 2 + kp;
    const unsigned short* ktile = kb  + (size_t)kt * TILE_USHORT;
    const unsigned short* vtile = vbI + (size_t)kt * TILE_USHORT;

    // --- K fragments (8 x contiguous 1 KB) + MFMA#1: S^T = K·Q^T ---
    uint4 kf[2][4];
    #pragma unroll
    for (int kk = 0; kk < 2; ++kk)
      #pragma unroll
      for (int ft = 0; ft < 4; ++ft)
        kf[kk][ft] = *(const uint4*)(ktile + (kk * 4 + ft) * 512 + lane * 8);

    floatx4 sc[4];   // [ft]: t = ft*16 + quad*4 + r, q = lq
    #pragma unroll
    for (int ft = 0; ft < 4; ++ft) sc[ft] = (floatx4){0.f, 0.f, 0.f, 0.f};
    #pragma unroll
    for (int kk = 0; kk < 2; ++kk) {
      short8 bq = *(const short8*)&qfrag[kk];
      #pragma unroll
      for (int ft = 0; ft < 4; ++ft)
        sc[ft] = __builtin_amdgcn_mfma_f32_16x16x32_bf16(
            *(const short8*)&kf[kk][ft], bq, sc[ft], 0, 0, 0);
    }

    // --- V fragments: issue now; latency hides under the transform ---
    uint4 vf[2][4];
    #pragma unroll
    for (int kk2 = 0; kk2 < 2; ++kk2)
      #pragma unroll
      for (int fd = 0; fd < 4; ++fd)
        vf[kk2][fd] = *(const uint4*)(vtile + (kk2 * 4 + fd) * 512 + lane * 8);

    // --- transform in place: sc := W = (1/2 + asin(d)/pi)^8 (packed f32) ---
    {
      float2v mxy = mk2(0.f);
      #pragma unroll
      for (int ft = 0; ft < 4; ++ft) {
        float2v* p = (float2v*)&sc[ft];
        mxy = max2(mxy, max2(abs2(p[0]), abs2(p[1])));
      }
      float mx = fmaxf(mxy[0], mxy[1]);
      if (__builtin_expect(__any(mx > 0.82f), 0)) {
        #pragma unroll
        for (int ft = 0; ft < 4; ++ft)
          #pragma unroll
          for (int r = 0; r < 4; ++r) {
            float f = yoso_f_exact(sc[ft][r]);
            float f2 = f * f;
            float f4 = f2 * f2;
            sc[ft][r] = f4 * f4;
          }
      } else {
        float2v c5 = mk2(P5), c4 = mk2(P4), c3 = mk2(P3), c2 = mk2(P2),
                c1 = mk2(P1), c0 = mk2(P0), hf = mk2(0.5f);
        #pragma unroll
        for (int ft = 0; ft < 4; ++ft) {
          float2v* p = (float2v*)&sc[ft];
          #pragma unroll
          for (int hh = 0; hh < 2; ++hh) {
            float2v d = p[hh];
            float2v y = d * d;
            float2v pp = ((((c5 * y + c4) * y + c3) * y + c2) * y + c1) * y + c0;
            float2v f = pp * d + hf;
            float2v f2 = f * f;
            float2v f4 = f2 * f2;
            p[hh] = f4 * f4;
          }
        }
      }
    }

    // --- MFMA#2: X^T += Vm^T · W^T (consumes vf) ---
    #pragma unroll
    for (int kk2 = 0; kk2 < 2; ++kk2) {
      uint4 u;
      u.x = pack_bf16_trunc(sc[2 * kk2][0], sc[2 * kk2][1]);
      u.y = pack_bf16_trunc(sc[2 * kk2][2], sc[2 * kk2][3]);
      u.z = pack_bf16_trunc(sc[2 * kk2 + 1][0], sc[2 * kk2 + 1][1]);
      u.w = pack_bf16_trunc(sc[2 * kk2 + 1][2], sc[2 * kk2 + 1][3]);
      short8 bw = *(short8*)&u;
      #pragma unroll
      for (int fd = 0; fd < 4; ++fd)
        acc[fd] = __builtin_amdgcn_mfma_f32_16x16x32_bf16(
            *(const short8*)&vf[kk2][fd], bw, acc[fd], 0, 0, 0);
    }
  }

  // --- k-parity reduction: (qs,1) exports, (qs,0) adds + finishes ---
  if (kp == 1) {
    float* wr = xch + qs * 1088;
    #pragma unroll
    for (int fd = 0; fd < 4; ++fd)
      #pragma unroll
      for (int r = 0; r < 4; ++r)
        wr[lq * 68 + fd * 16 + quad * 4 + r] = acc[fd][r];
  }
  __syncthreads();
  if (kp == 0) {
    const float* rd = xch + qs * 1088;
    #pragma unroll
    for (int fd = 0; fd < 4; ++fd)
      #pragma unroll
      for (int r = 0; r < 4; ++r)
        acc[fd][r] += rd[lq * 68 + fd * 16 + quad * 4 + r];

    // --- epilogue: q = s0 + qs*16 + lq ---
    int s = s0 + qs * 16 + lq;
    float qm  = mask[b * NS + s];
    float qm0 = (s > 0) ? mask[b * NS + s - 1] : 0.f;
    float qm2 = (s < NS - 1) ? mask[b * NS + s + 1] : 0.f;
    float ssum = 0.f;
    #pragma unroll
    for (int fd = 0; fd < 4; ++fd)
      #pragma unroll
      for (int r = 0; r < 4; ++r) {
        float x = acc[fd][r] * qm;
        acc[fd][r] = x;
        ssum += x * x;
      }
    ssum += __shfl_xor(ssum, 16, 64);
    ssum += __shfl_xor(ssum, 32, 64);
    float rn = 1.0f / fmaxf(sqrtf(ssum), 1e-12f);

    const float* vfull = V + ((size_t)bh * NS + s) * ND;
    #pragma unroll
    for (int fd = 0; fd < 4; ++fd) {
      int d = fd * 16 + quad * 4;
      float4 vc1 = *(const float4*)(vfull + d);
      float4 cv;
      cv.x = w1 * vc1.x * qm; cv.y = w1 * vc1.y * qm;
      cv.z = w1 * vc1.z * qm; cv.w = w1 * vc1.w * qm;
      if (s > 0) {
        float4 vc0 = *(const float4*)(vfull - ND + d);
        cv.x += w0 * vc0.x * qm0; cv.y += w0 * vc0.y * qm0;
        cv.z += w0 * vc0.z * qm0; cv.w += w0 * vc0.w * qm0;
      }
      if (s < NS - 1) {
        float4 vc2 = *(const float4*)(vfull + ND + d);
        cv.x += w2 * vc2.x * qm2; cv.y += w2 * vc2.y * qm2;
        cv.z += w2 * vc2.z * qm2; cv.w += w2 * vc2.w * qm2;
      }
      float4 o;
      o.x = acc[fd][0] * rn + cv.x;
      o.y = acc[fd][1] * rn + cv.y;
      o.z = acc[fd][2] * rn + cv.z;
      o.w = acc[fd][3] * rn + cv.w;
      *(float4*)(out + ((size_t)bh * NS + s) * ND + d) = o;
    }
  }
}

// ---------------------------------------------------------------------------
extern "C" void kernel_launch(void* const* d_in, const int* in_sizes, int n_in,
                              void* d_out, int out_size, void* d_ws, size_t ws_size,
                              hipStream_t stream) {
  const float* Q      = (const float*)d_in[0];
  const float* K      = (const float*)d_in[1];
  const float* V      = (const float*)d_in[2];
  const float* mask   = (const float*)d_in[3];
  const float* conv_w = (const float*)d_in[4];
  float* out = (float*)d_out;

  const size_t seg = (size_t)NBH * NS * ND * sizeof(unsigned short);  // 6.29 MB
  unsigned short* qimg = (unsigned short*)d_ws;
  unsigned short* kimg = (unsigned short*)((char*)d_ws + seg);
  unsigned short* vimg = (unsigned short*)((char*)d_ws + 2 * seg);

  prep_all<<<QK_BLOCKS + V_BLOCKS, 256, 0, stream>>>(Q, K, V, mask, qimg, kimg, vimg);
  yoso_main<<<NBH * 64, 256, 0, stream>>>(qimg, kimg, vimg, V, mask, conv_w, out);
}